// Round 12
// baseline (16167.586 us; speedup 1.0000x reference)
//
#include <hip/hip_runtime.h>
#include <hip/hip_bf16.h>

// ============================================================================
// 2-layer quirky LSTM, persistent kernel, round 12.
// Numerics (r8-validated): fp16 W/h/x single plane, f32 c; absmax 0.125.
// r11 lesson: barrier topology is not the wall; the wall is that ALL work sat
// behind the h1 handoff. Only ~25% of L1 FLOPs depend on h1[t-1]; h0[t] is
// ready LAG phases early. This round: PREWORK — between posting arrival and
// the own-domain poll, compute everything that doesn't need the new h1/h0:
//   L0 prework: x[t+1] prefetch + x-GEMM (both kh waves, 8 chunks each)
//   L1 prework: full h0-part (32 chunks; kh0 streams W K[0,512) from L2,
//               kh1 uses LDS) guarded by partner-epoch check
//   post-barrier tail: 16 chunks (h0-part for L0 / h1-part for L1), all-LDS
// L1 LDS now holds W1 K[512,2048) so the critical tail never touches global.
// Domains/backpressure/ring-16/inv-per-16 from r11 (validated).
// ============================================================================

typedef __attribute__((ext_vector_type(8))) _Float16 f16x8;
typedef __attribute__((ext_vector_type(4))) float f32x4;
typedef unsigned long long u64;
#define DEV __device__ __forceinline__

namespace {
constexpr int Bb = 128, Ss = 1024, Ii = 512, Hh = 1024;
constexpr int K0 = Ii + Hh;            // 1536
constexpr int K1 = 2 * Hh;             // 2048
constexpr int NWG = 256;               // 1 WG/CU, 512 threads
constexpr int NPH = Ss + 1;
constexpr int RING = 16;               // h ring depth (= inv period)
constexpr int LAG  = 12;               // max L0 lead (<= 14 for prework safety)
constexpr int SSTR = 32;               // slot stride in ints (128 B)

constexpr size_t BH    = (size_t)Bb * Hh;              // 131072
constexpr size_t OF_H0 = (size_t)Bb * Ss * Hh;
constexpr size_t OF_C0 = OF_H0 + BH;
constexpr size_t OF_H1 = OF_C0 + BH;
constexpr size_t OF_C1 = OF_H1 + BH;

// workspace
constexpr size_t WS_SLOTS = 4096;                    // 4 domains x 64 x 128 B
constexpr size_t WS_C0    = 40960;                   // f32 [B][H]
constexpr size_t WS_C1    = WS_C0 + BH * 4;
constexpr size_t RINGF    = (size_t)RING * BH * 2;   // 4 MB per layer plane
constexpr size_t WS_H0F   = WS_C1 + BH * 4;          // fp16 ring [16][B][H]
constexpr size_t WS_H1F   = WS_H0F + RINGF;
constexpr size_t WS_ZEND  = WS_H1F + RINGF;          // ~9.0 MB zeroed/launch
constexpr size_t WSZ_W0   = (size_t)3 * Hh * K0 * 2; // 9.4 MB
constexpr size_t WSZ_W1   = (size_t)3 * Hh * K1 * 2; // 12.6 MB
constexpr size_t WS_W0F   = WS_ZEND;
constexpr size_t WS_W1F   = WS_W0F + WSZ_W0;
constexpr size_t WS_NEED  = WS_W1F + WSZ_W1;         // ~30 MB

// LDS W: [48 k-chunks][3 gates][4 l4][16 l15][16B]  (3072 B per chunk)
// L0: W K[0,1536).  L1: W K[512,2048)  (chunk ch = (Wk - kbase)/32).
constexpr int CHUNKB    = 3072;
constexpr int LO_BYTES  = 48 * CHUNKB;              // 147456
constexpr int RED_BYTES = 4 * 3 * 64 * 16;          // 12288
constexpr int DYN_LDS   = LO_BYTES + RED_BYTES;     // 159744 <= 160 KiB
}

DEV unsigned short f16b(float f) {
  return __builtin_bit_cast(unsigned short, (_Float16)f);
}
DEV float sig_(float x) { return 1.f / (1.f + __expf(-x)); }
DEV float tanh_(float x) {
  float e = __expf(-2.f * fabsf(x));
  return copysignf((1.f - e) / (1.f + e), x);
}
DEV f16x8 ldh(const unsigned short* p) { return *reinterpret_cast<const f16x8*>(p); }
#define MFMAH __builtin_amdgcn_mfma_f32_16x16x32_f16

// ---------------------------------------------------------------------------
__global__ void k_zero(uint4* p, int n16) {
  for (int i = blockIdx.x * blockDim.x + threadIdx.x; i < n16; i += gridDim.x * blockDim.x)
    p[i] = make_uint4(0u, 0u, 0u, 0u);
}

// W f32 -> fp16 single plane
__global__ void k_convert(const float* __restrict__ W0, const float* __restrict__ W1,
                          unsigned short* __restrict__ w0f, unsigned short* __restrict__ w1f) {
  const long NW04 = (long)3 * Hh * K0 / 4;
  const long NW14 = (long)3 * Hh * K1 / 4;
  const long total = NW04 + NW14;
  for (long i = (long)blockIdx.x * blockDim.x + threadIdx.x; i < total;
       i += (long)gridDim.x * blockDim.x) {
    long e; const float* src; unsigned short* dst;
    if (i < NW04) { e = i * 4;          src = W0 + e; dst = w0f + e; }
    else          { e = (i - NW04) * 4; src = W1 + e; dst = w1f + e; }
    f32x4 v = *(const f32x4*)src;
    u64 pk = 0;
#pragma unroll
    for (int e2 = 0; e2 < 4; ++e2) pk |= (u64)f16b(v[e2]) << (16 * e2);
    *(u64*)dst = pk;
  }
}

// ---------------------------------------------------------------------------
// W fragment from LDS by chunk index (lane-linear, conflict-free)
#define LD_WC(g, ch)                                                          \
  (*(const f16x8*)(lds + (ch) * CHUNKB + (g) * 1024 + l4 * 256 + l15 * 16))

#define HLOAD(arr, n, hP, kaB)                                                \
  _Pragma("unroll") for (int c_ = 0; c_ < (n); ++c_)                          \
    arr[c_] = ldh((hP) + (kaB) + c_ * 32);

// compute n chunks, W from LDS at chunk base cB (compile-time)
#define HCOMP(arr, n, cB)                                                     \
  _Pragma("unroll") for (int c_ = 0; c_ < (n); ++c_) {                        \
    f32x4 &I_ = (c_ & 1) ? aI1 : aI0;                                         \
    f32x4 &G_ = (c_ & 1) ? aG1 : aG0;                                         \
    f32x4 &O_ = (c_ & 1) ? aO1 : aO0;                                         \
    I_ = MFMAH(LD_WC(0, (cB) + c_), arr[c_], I_, 0, 0, 0);                    \
    G_ = MFMAH(LD_WC(1, (cB) + c_), arr[c_], G_, 0, 0, 0);                    \
    O_ = MFMAH(LD_WC(2, (cB) + c_), arr[c_], O_, 0, 0, 0);                    \
  }

// issue n W-chunk loads from global at absolute W-K base koB
#define WLOAD(a0, a1, a2, n, koB)                                             \
  _Pragma("unroll") for (int c_ = 0; c_ < (n); ++c_) {                        \
    const int ko_ = (koB) + c_ * 32;                                          \
    a0[c_] = ldh(wf + off0 + ko_);                                            \
    a1[c_] = ldh(wf + off1 + ko_);                                            \
    a2[c_] = ldh(wf + off2 + ko_);                                            \
  }

#define GCOMP(h_, a0, a1, a2, n)                                              \
  _Pragma("unroll") for (int c_ = 0; c_ < (n); ++c_) {                        \
    f32x4 &I_ = (c_ & 1) ? aI1 : aI0;                                         \
    f32x4 &G_ = (c_ & 1) ? aG1 : aG0;                                         \
    f32x4 &O_ = (c_ & 1) ? aO1 : aO0;                                         \
    I_ = MFMAH(a0[c_], h_[c_], I_, 0, 0, 0);                                  \
    G_ = MFMAH(a1[c_], h_[c_], G_, 0, 0, 0);                                  \
    O_ = MFMAH(a2[c_], h_[c_], O_, 0, 0, 0);                                  \
  }

// prefetch+scale+convert 8 x-chunks (this wave's kh half) into xp[8]
#define XPREF8(tn)                                                            \
  do {                                                                        \
    const float* pxn_ = xf + ((size_t)bact * Ss + (tn)) * Ii + khk + l4 * 8;  \
    const float twn_ = tw[tn] * emag;                                         \
    _Pragma("unroll") for (int c_ = 0; c_ < 8; ++c_) {                        \
      const int k_ = c_ * 32;                                                 \
      f32x4 a0_ = *(const f32x4*)(pxn_ + k_);                                 \
      f32x4 a1_ = *(const f32x4*)(pxn_ + k_ + 4);                             \
      f32x4 b0_ = *(const f32x4*)(fw + khk + k_ + l4 * 8);                    \
      f32x4 b1_ = *(const f32x4*)(fw + khk + k_ + l4 * 8 + 4);                \
      a0_ *= b0_ * twn_; a1_ *= b1_ * twn_;                                   \
      _Pragma("unroll") for (int e_ = 0; e_ < 4; ++e_) {                      \
        xp[c_][e_] = (_Float16)a0_[e_];                                       \
        xp[c_][e_ + 4] = (_Float16)a1_[e_];                                   \
      }                                                                       \
    }                                                                         \
  } while (0)

// 24 MFMAs from the 8 prefetched x fragments (W K chunks kh*8 .. kh*8+7)
#define XCOMP8() HCOMP(xp, 8, khc)

#define ZACC() do { f32x4 z_ = {0.f,0.f,0.f,0.f};                             \
    aI0 = z_; aG0 = z_; aO0 = z_; aI1 = z_; aG1 = z_; aO1 = z_; } while (0)

__global__ __launch_bounds__(512, 1) void lstm_persist(
    const float* __restrict__ xf,
    const float* __restrict__ fw, const float* __restrict__ tw, const float* __restrict__ mag,
    const unsigned short* __restrict__ w0f, const float* __restrict__ b0,
    const unsigned short* __restrict__ w1f, const float* __restrict__ b1,
    float* __restrict__ out,
    unsigned short* __restrict__ h0f, unsigned short* __restrict__ h1f,
    float* __restrict__ c0, float* __restrict__ c1,
    int* __restrict__ slots) {
  extern __shared__ char lds[];
  f32x4* red = reinterpret_cast<f32x4*>(lds + LO_BYTES);

  const int tid = threadIdx.x;
  const int lane = tid & 63;
  const int wv = tid >> 6;               // 0..7
  const int mt = wv & 3;                 // row subtile (16 rows)
  const int kh = wv >> 2;                // K-half
  const int l15 = lane & 15, l4 = lane >> 4;
  const int khk = kh * 256;              // x k-base for this wave
  const int khc = kh * 8;                // x LDS chunk base (L0)

  const int wg = blockIdx.x;
  const int layer = wg >> 7;
  const int i = wg & 127;
  const int x8 = i & 7;                  // ~XCD (wg%8 round-robin heuristic)
  const int kk = i >> 3;                 // 0..15
  const int mg = x8 >> 2;                // XCD 0-3 -> rows 0-63, 4-7 -> 64-127
  const int jt = (x8 & 3) * 16 + kk;     // 0..63
  const int jb = jt * 16;

  const int dom  = layer * 2 + mg;       // sync domain (64 WGs)
  const int pdom = layer ? mg : 2 + mg;  // partner domain (other layer)
  const int idx  = (x8 & 3) * 16 + kk;

  const int bact = mg * 64 + mt * 16 + l15;   // batch row
  const int j0 = jb + l4 * 4;

  const int K = layer ? K1 : K0;
  const int KB = layer ? 512 : 0;        // LDS W k-base
  const unsigned short* wf = layer ? w1f : w0f;
  const size_t off0 = (size_t)(0 * Hh + jb + l15) * K + l4 * 8;
  const size_t off1 = (size_t)(1 * Hh + jb + l15) * K + l4 * 8;
  const size_t off2 = (size_t)(2 * Hh + jb + l15) * K + l4 * 8;

  const float* bb = layer ? b1 : b0;
  const f32x4 bi = *(const f32x4*)(bb + j0);
  const f32x4 bg = *(const f32x4*)(bb + Hh + j0);
  const f32x4 bo = *(const f32x4*)(bb + 2 * Hh + j0);

  float* cst = (layer ? c1 : c0) + (size_t)bact * Hh + j0;
  float* outb = out + (size_t)bact * Ss * Hh + j0;
  const float emag = __expf(mag[0]);

  // ---- prologue: W slice (48 rows x 1536 cols from KB) -> LDS ----
  {
    const u64* wsl = (const u64*)wf;
    const int K4 = K >> 2;
    const int cb4 = KB >> 2;
    for (int q = tid; q < 48 * 384; q += 512) {
      int R = q / 384;                   // 0..47 = g*16 + rr
      int o = q - R * 384;               // u64 col within LDS window
      int g = R >> 4, rr = R & 15;
      u64 v = wsl[(size_t)(g * Hh + jb + rr) * K4 + cb4 + o];
      *(u64*)(lds + (o >> 3) * CHUNKB + g * 1024 + ((o >> 1) & 3) * 256 +
              rr * 16 + (o & 1) * 8) = v;
    }
  }
  __syncthreads();

  f32x4 aI0, aG0, aO0, aI1, aG1, aO1;
  ZACC();
  f16x8 xp[8];
  if (layer == 0) { XPREF8(0); XCOMP8(); }   // prework for phase 0

  for (int p = 0; p < NPH; ++p) {
    const bool act = layer ? (p >= 1) : (p < Ss);
    const int t = layer ? (p - 1) : p;
    const int rslot = (p - 1) & (RING - 1);
    const int wslot = p & (RING - 1);

    if (act) {
      // ---- post-barrier tail: the only phase-serial GEMM work ----
      const unsigned short* hr =
          (layer ? h1f : h0f) + (size_t)rslot * BH + (size_t)bact * Hh + l4 * 8;
      if (kh == 0) {
        f16x8 hA[8], hB[8];
        HLOAD(hA, 8, hr, 0); HLOAD(hB, 8, hr, 256);
        HCOMP(hA, 8, 16); HCOMP(hB, 8, 24);
      } else {
        f16x8 hA[8], hB[8];
        HLOAD(hA, 8, hr, 512); HLOAD(hB, 8, hr, 768);
        HCOMP(hA, 8, 32); HCOMP(hB, 8, 40);
      }

      if (kh == 1) {
        red[((mt * 3 + 0) << 6) + lane] = aI0 + aI1;
        red[((mt * 3 + 1) << 6) + lane] = aG0 + aG1;
        red[((mt * 3 + 2) << 6) + lane] = aO0 + aO1;
      }
      __syncthreads();
      if (kh == 0) {
        f32x4 ai = aI0 + aI1 + red[((mt * 3 + 0) << 6) + lane] + bi;
        f32x4 ag = aG0 + aG1 + red[((mt * 3 + 1) << 6) + lane] + bg;
        f32x4 ao = aO0 + aO1 + red[((mt * 3 + 2) << 6) + lane] + bo;
        f32x4 cp = *(const f32x4*)cst;
        f32x4 cn, hn;
        u64 hpk = 0;
#pragma unroll
        for (int r = 0; r < 4; ++r) {
          float f = sig_(cp[r]);                   // forget gate from c_prev (quirk)
          float cc = f * cp[r] + sig_(ai[r]) * tanh_(ag[r]);
          float hh = sig_(ao[r]) * tanh_(cc) * f;  // extra *f (quirk)
          cn[r] = cc; hn[r] = hh;
          hpk |= (u64)f16b(hh) << (16 * r);
        }
        *(f32x4*)cst = cn;
        const size_t wbase = (size_t)wslot * BH + (size_t)bact * Hh + j0;
        __hip_atomic_store((u64*)((layer ? h1f : h0f) + wbase), hpk,
                           __ATOMIC_RELAXED, __HIP_MEMORY_SCOPE_AGENT);
        if (layer) {
          *(f32x4*)(outb + (size_t)t * Hh) = hn;
          if (t == Ss - 1) {
            *(f32x4*)(out + OF_H1 + (size_t)bact * Hh + j0) = hn;
            *(f32x4*)(out + OF_C1 + (size_t)bact * Hh + j0) = cn;
          }
        } else if (t == Ss - 1) {
          *(f32x4*)(out + OF_H0 + (size_t)bact * Hh + j0) = hn;
          *(f32x4*)(out + OF_C0 + (size_t)bact * Hh + j0) = cn;
        }
      }
    }

    // ---- barrier section with PREWORK ----
    if (p < NPH - 1) {
      __syncthreads();   // main done; vmcnt drained -> h stores at LLC
      // ring-boundary inv BEFORE any new-window reads (prework included)
      if ((p & (RING - 1)) == (RING - 1)) {
        if (tid == 0) __builtin_amdgcn_fence(__ATOMIC_ACQUIRE, "agent");
        __syncthreads();
      }
      if (tid == 0)
        __hip_atomic_store(&slots[(dom * 64 + idx) * SSTR], p + 1,
                           __ATOMIC_RELAXED, __HIP_MEMORY_SCOPE_AGENT);

      if (layer == 1) {
        // partner gate: h0[t=p] ready (L0 epoch >= p+1) before prework reads
        bool ok = (tid >= 64);
        int gd = 0;
        do {
          if (!ok)
            ok = __hip_atomic_load(&slots[(pdom * 64 + tid) * SSTR],
                                   __ATOMIC_RELAXED,
                                   __HIP_MEMORY_SCOPE_AGENT) >= p + 1;
          if (!ok) __builtin_amdgcn_s_sleep(2);
        } while (!__syncthreads_and(ok) && ++gd < (1 << 22));
        // prework(p+1): full h0-part (no h1 dependence)
        ZACC();
        const unsigned short* h0n =
            h0f + (size_t)(p & (RING - 1)) * BH + (size_t)bact * Hh + l4 * 8;
        if (kh == 0) {  // W K[0,512) streamed from global (L2-resident)
          {
            f16x8 sh[6], sA[6], sB[6], sC[6];
            HLOAD(sh, 6, h0n, 0); WLOAD(sA, sB, sC, 6, 0);
            GCOMP(sh, sA, sB, sC, 6);
          }
          {
            f16x8 sh[6], sA[6], sB[6], sC[6];
            HLOAD(sh, 6, h0n, 192); WLOAD(sA, sB, sC, 6, 192);
            GCOMP(sh, sA, sB, sC, 6);
          }
          {
            f16x8 sh[4], sA[4], sB[4], sC[4];
            HLOAD(sh, 4, h0n, 384); WLOAD(sA, sB, sC, 4, 384);
            GCOMP(sh, sA, sB, sC, 4);
          }
        } else {        // W K[512,1024) = LDS chunks 0..15
          f16x8 hA[8], hB[8];
          HLOAD(hA, 8, h0n, 512); HLOAD(hB, 8, h0n, 768);
          HCOMP(hA, 8, 0); HCOMP(hB, 8, 8);
        }
        // own-domain barrier: h1[t=p] ready
        ok = (tid >= 64);
        gd = 0;
        do {
          if (!ok)
            ok = __hip_atomic_load(&slots[(dom * 64 + tid) * SSTR],
                                   __ATOMIC_RELAXED,
                                   __HIP_MEMORY_SCOPE_AGENT) >= p + 1;
          if (!ok) __builtin_amdgcn_s_sleep(2);
        } while (!__syncthreads_and(ok) && ++gd < (1 << 22));
      } else {
        // L0 prework(p+1): x part (no dependence at all)
        if (p + 1 < Ss) { XPREF8(p + 1); ZACC(); XCOMP8(); }
        // own-domain barrier + backpressure (ring overwrite guard)
        const int pthr = p + 1 - LAG;
        bool ok;
        if (tid < 64)        ok = false;
        else if (tid < 128)  ok = (pthr <= 0);
        else                 ok = true;
        int gd = 0;
        do {
          if (!ok) {
            int v = (tid < 64)
                ? __hip_atomic_load(&slots[(dom * 64 + tid) * SSTR],
                                    __ATOMIC_RELAXED, __HIP_MEMORY_SCOPE_AGENT)
                : __hip_atomic_load(&slots[(pdom * 64 + (tid - 64)) * SSTR],
                                    __ATOMIC_RELAXED, __HIP_MEMORY_SCOPE_AGENT);
            ok = v >= ((tid < 64) ? (p + 1) : pthr);
          }
          if (!ok) __builtin_amdgcn_s_sleep(2);
        } while (!__syncthreads_and(ok) && ++gd < (1 << 22));
      }
    }
  }
}

// ---------------------------------------------------------------------------
extern "C" void kernel_launch(void* const* d_in, const int* in_sizes, int n_in,
                              void* d_out, int out_size, void* d_ws, size_t ws_size,
                              hipStream_t stream) {
  const float* x   = (const float*)d_in[0];
  const float* fw  = (const float*)d_in[1];
  const float* tw  = (const float*)d_in[2];
  const float* mag = (const float*)d_in[3];
  const float* W0  = (const float*)d_in[4];
  const float* b0  = (const float*)d_in[5];
  const float* W1  = (const float*)d_in[6];
  const float* b1  = (const float*)d_in[7];
  float* out = (float*)d_out;
  char* ws = (char*)d_ws;

  if (ws_size < WS_NEED) return;

  unsigned short* w0f = (unsigned short*)(ws + WS_W0F);
  unsigned short* w1f = (unsigned short*)(ws + WS_W1F);

  (void)hipFuncSetAttribute((const void*)lstm_persist,
                            hipFuncAttributeMaxDynamicSharedMemorySize, DYN_LDS);

  k_zero<<<2048, 256, 0, stream>>>((uint4*)ws, (int)(WS_ZEND / 16));
  k_convert<<<1024, 256, 0, stream>>>(W0, W1, w0f, w1f);

  lstm_persist<<<NWG, 512, DYN_LDS, stream>>>(
      x, fw, tw, mag, w0f, b0, w1f, b1, out,
      (unsigned short*)(ws + WS_H0F), (unsigned short*)(ws + WS_H1F),
      (float*)(ws + WS_C0), (float*)(ws + WS_C1),
      (int*)(ws + WS_SLOTS));
}

// Round 13
// 15456.354 us; speedup vs baseline: 1.0460x; 1.0460x over previous
//
#include <hip/hip_runtime.h>
#include <hip/hip_bf16.h>

// ============================================================================
// 2-layer quirky LSTM, persistent kernel, round 13.
// Numerics (r8-validated): fp16 W/h/x single plane, f32 c; absmax 0.125.
// r12 diagnosis: with RING=16 the h rings rotate 4MB/XCD through L2 every 16
// phases -> L2 never held the working set; stragglers set barrier time.
// This round:
//  1. RING=4, LAG=2 -> per-XCD working set ~2.8MB < 4MB L2 (first fit)
//  2. wave0-only sticky polling (others sleep at __syncthreads)
//  3. L1 prework W-global stream batched 8+8
// Everything else (domains, prework split, LDS layouts) = r12 (validated).
// ============================================================================

typedef __attribute__((ext_vector_type(8))) _Float16 f16x8;
typedef __attribute__((ext_vector_type(4))) float f32x4;
typedef unsigned long long u64;
#define DEV __device__ __forceinline__

namespace {
constexpr int Bb = 128, Ss = 1024, Ii = 512, Hh = 1024;
constexpr int K0 = Ii + Hh;            // 1536
constexpr int K1 = 2 * Hh;             // 2048
constexpr int NWG = 256;               // 1 WG/CU, 512 threads
constexpr int NPH = Ss + 1;
constexpr int RING = 4;                // h ring depth (= inv period)
constexpr int LAG  = 2;                // max L0 lead (safe: margin proof r13)
constexpr int SSTR = 32;               // slot stride in ints (128 B)

constexpr size_t BH    = (size_t)Bb * Hh;              // 131072
constexpr size_t OF_H0 = (size_t)Bb * Ss * Hh;
constexpr size_t OF_C0 = OF_H0 + BH;
constexpr size_t OF_H1 = OF_C0 + BH;
constexpr size_t OF_C1 = OF_H1 + BH;

// workspace
constexpr size_t WS_SLOTS = 4096;                    // 4 domains x 64 x 128 B
constexpr size_t WS_C0    = 40960;                   // f32 [B][H]
constexpr size_t WS_C1    = WS_C0 + BH * 4;
constexpr size_t RINGF    = (size_t)RING * BH * 2;   // 1 MB per layer plane
constexpr size_t WS_H0F   = WS_C1 + BH * 4;          // fp16 ring [4][B][H]
constexpr size_t WS_H1F   = WS_H0F + RINGF;
constexpr size_t WS_ZEND  = WS_H1F + RINGF;          // ~3.1 MB zeroed/launch
constexpr size_t WSZ_W0   = (size_t)3 * Hh * K0 * 2; // 9.4 MB
constexpr size_t WSZ_W1   = (size_t)3 * Hh * K1 * 2; // 12.6 MB
constexpr size_t WS_W0F   = WS_ZEND;
constexpr size_t WS_W1F   = WS_W0F + WSZ_W0;
constexpr size_t WS_NEED  = WS_W1F + WSZ_W1;         // ~25 MB

// LDS W: [48 k-chunks][3 gates][4 l4][16 l15][16B]  (3072 B per chunk)
// L0: W K[0,1536).  L1: W K[512,2048).
constexpr int CHUNKB    = 3072;
constexpr int LO_BYTES  = 48 * CHUNKB;              // 147456
constexpr int RED_BYTES = 4 * 3 * 64 * 16;          // 12288
constexpr int DYN_LDS   = LO_BYTES + RED_BYTES;     // 159744 <= 160 KiB
}

DEV unsigned short f16b(float f) {
  return __builtin_bit_cast(unsigned short, (_Float16)f);
}
DEV float sig_(float x) { return 1.f / (1.f + __expf(-x)); }
DEV float tanh_(float x) {
  float e = __expf(-2.f * fabsf(x));
  return copysignf((1.f - e) / (1.f + e), x);
}
DEV f16x8 ldh(const unsigned short* p) { return *reinterpret_cast<const f16x8*>(p); }
#define MFMAH __builtin_amdgcn_mfma_f32_16x16x32_f16

// wave-level sticky polls (called by wave 0 only; lane l owns slot base+l)
DEV void poll1(const int* slots, int base, int thr, int lane) {
  bool ok = false;
  for (int gd = 0; gd < (1 << 24); ++gd) {
    if (!ok)
      ok = __hip_atomic_load(&slots[(base + lane) * SSTR], __ATOMIC_RELAXED,
                             __HIP_MEMORY_SCOPE_AGENT) >= thr;
    if (__all(ok)) break;
    __builtin_amdgcn_s_sleep(1);
  }
}
DEV void poll2(const int* slots, int b1, int t1, int b2, int t2, int lane) {
  bool ok1 = false, ok2 = (t2 <= 0);
  for (int gd = 0; gd < (1 << 24); ++gd) {
    if (!ok1)
      ok1 = __hip_atomic_load(&slots[(b1 + lane) * SSTR], __ATOMIC_RELAXED,
                              __HIP_MEMORY_SCOPE_AGENT) >= t1;
    if (!ok2)
      ok2 = __hip_atomic_load(&slots[(b2 + lane) * SSTR], __ATOMIC_RELAXED,
                              __HIP_MEMORY_SCOPE_AGENT) >= t2;
    if (__all(ok1 && ok2)) break;
    __builtin_amdgcn_s_sleep(1);
  }
}

// ---------------------------------------------------------------------------
__global__ void k_zero(uint4* p, int n16) {
  for (int i = blockIdx.x * blockDim.x + threadIdx.x; i < n16; i += gridDim.x * blockDim.x)
    p[i] = make_uint4(0u, 0u, 0u, 0u);
}

// W f32 -> fp16 single plane
__global__ void k_convert(const float* __restrict__ W0, const float* __restrict__ W1,
                          unsigned short* __restrict__ w0f, unsigned short* __restrict__ w1f) {
  const long NW04 = (long)3 * Hh * K0 / 4;
  const long NW14 = (long)3 * Hh * K1 / 4;
  const long total = NW04 + NW14;
  for (long i = (long)blockIdx.x * blockDim.x + threadIdx.x; i < total;
       i += (long)gridDim.x * blockDim.x) {
    long e; const float* src; unsigned short* dst;
    if (i < NW04) { e = i * 4;          src = W0 + e; dst = w0f + e; }
    else          { e = (i - NW04) * 4; src = W1 + e; dst = w1f + e; }
    f32x4 v = *(const f32x4*)src;
    u64 pk = 0;
#pragma unroll
    for (int e2 = 0; e2 < 4; ++e2) pk |= (u64)f16b(v[e2]) << (16 * e2);
    *(u64*)dst = pk;
  }
}

// ---------------------------------------------------------------------------
// W fragment from LDS by chunk index (lane-linear, conflict-free)
#define LD_WC(g, ch)                                                          \
  (*(const f16x8*)(lds + (ch) * CHUNKB + (g) * 1024 + l4 * 256 + l15 * 16))

#define HLOAD(arr, n, hP, kaB)                                                \
  _Pragma("unroll") for (int c_ = 0; c_ < (n); ++c_)                          \
    arr[c_] = ldh((hP) + (kaB) + c_ * 32);

#define HCOMP(arr, n, cB)                                                     \
  _Pragma("unroll") for (int c_ = 0; c_ < (n); ++c_) {                        \
    f32x4 &I_ = (c_ & 1) ? aI1 : aI0;                                         \
    f32x4 &G_ = (c_ & 1) ? aG1 : aG0;                                         \
    f32x4 &O_ = (c_ & 1) ? aO1 : aO0;                                         \
    I_ = MFMAH(LD_WC(0, (cB) + c_), arr[c_], I_, 0, 0, 0);                    \
    G_ = MFMAH(LD_WC(1, (cB) + c_), arr[c_], G_, 0, 0, 0);                    \
    O_ = MFMAH(LD_WC(2, (cB) + c_), arr[c_], O_, 0, 0, 0);                    \
  }

#define WLOAD(a0, a1, a2, n, koB)                                             \
  _Pragma("unroll") for (int c_ = 0; c_ < (n); ++c_) {                        \
    const int ko_ = (koB) + c_ * 32;                                          \
    a0[c_] = ldh(wf + off0 + ko_);                                            \
    a1[c_] = ldh(wf + off1 + ko_);                                            \
    a2[c_] = ldh(wf + off2 + ko_);                                            \
  }

#define GCOMP(h_, a0, a1, a2, n)                                              \
  _Pragma("unroll") for (int c_ = 0; c_ < (n); ++c_) {                        \
    f32x4 &I_ = (c_ & 1) ? aI1 : aI0;                                         \
    f32x4 &G_ = (c_ & 1) ? aG1 : aG0;                                         \
    f32x4 &O_ = (c_ & 1) ? aO1 : aO0;                                         \
    I_ = MFMAH(a0[c_], h_[c_], I_, 0, 0, 0);                                  \
    G_ = MFMAH(a1[c_], h_[c_], G_, 0, 0, 0);                                  \
    O_ = MFMAH(a2[c_], h_[c_], O_, 0, 0, 0);                                  \
  }

// prefetch+scale+convert 8 x-chunks (this wave's kh half) into xp[8]
#define XPREF8(tn)                                                            \
  do {                                                                        \
    const float* pxn_ = xf + ((size_t)bact * Ss + (tn)) * Ii + khk + l4 * 8;  \
    const float twn_ = tw[tn] * emag;                                         \
    _Pragma("unroll") for (int c_ = 0; c_ < 8; ++c_) {                        \
      const int k_ = c_ * 32;                                                 \
      f32x4 a0_ = *(const f32x4*)(pxn_ + k_);                                 \
      f32x4 a1_ = *(const f32x4*)(pxn_ + k_ + 4);                             \
      f32x4 b0_ = *(const f32x4*)(fw + khk + k_ + l4 * 8);                    \
      f32x4 b1_ = *(const f32x4*)(fw + khk + k_ + l4 * 8 + 4);                \
      a0_ *= b0_ * twn_; a1_ *= b1_ * twn_;                                   \
      _Pragma("unroll") for (int e_ = 0; e_ < 4; ++e_) {                      \
        xp[c_][e_] = (_Float16)a0_[e_];                                       \
        xp[c_][e_ + 4] = (_Float16)a1_[e_];                                   \
      }                                                                       \
    }                                                                         \
  } while (0)

#define XCOMP8() HCOMP(xp, 8, khc)

#define ZACC() do { f32x4 z_ = {0.f,0.f,0.f,0.f};                             \
    aI0 = z_; aG0 = z_; aO0 = z_; aI1 = z_; aG1 = z_; aO1 = z_; } while (0)

__global__ __launch_bounds__(512, 1) void lstm_persist(
    const float* __restrict__ xf,
    const float* __restrict__ fw, const float* __restrict__ tw, const float* __restrict__ mag,
    const unsigned short* __restrict__ w0f, const float* __restrict__ b0,
    const unsigned short* __restrict__ w1f, const float* __restrict__ b1,
    float* __restrict__ out,
    unsigned short* __restrict__ h0f, unsigned short* __restrict__ h1f,
    float* __restrict__ c0, float* __restrict__ c1,
    int* __restrict__ slots) {
  extern __shared__ char lds[];
  f32x4* red = reinterpret_cast<f32x4*>(lds + LO_BYTES);

  const int tid = threadIdx.x;
  const int lane = tid & 63;
  const int wv = tid >> 6;               // 0..7
  const int mt = wv & 3;                 // row subtile (16 rows)
  const int kh = wv >> 2;                // K-half
  const int l15 = lane & 15, l4 = lane >> 4;
  const int khk = kh * 256;              // x k-base for this wave
  const int khc = kh * 8;                // x LDS chunk base (L0)

  const int wg = blockIdx.x;
  const int layer = wg >> 7;
  const int i = wg & 127;
  const int x8 = i & 7;                  // ~XCD (wg%8 round-robin heuristic)
  const int kk = i >> 3;                 // 0..15
  const int mg = x8 >> 2;                // XCD 0-3 -> rows 0-63, 4-7 -> 64-127
  const int jt = (x8 & 3) * 16 + kk;     // 0..63
  const int jb = jt * 16;

  const int dom  = layer * 2 + mg;       // sync domain (64 WGs)
  const int pdom = layer ? mg : 2 + mg;  // partner domain (other layer)
  const int idx  = (x8 & 3) * 16 + kk;

  const int bact = mg * 64 + mt * 16 + l15;   // batch row
  const int j0 = jb + l4 * 4;

  const int K = layer ? K1 : K0;
  const int KB = layer ? 512 : 0;        // LDS W k-base
  const unsigned short* wf = layer ? w1f : w0f;
  const size_t off0 = (size_t)(0 * Hh + jb + l15) * K + l4 * 8;
  const size_t off1 = (size_t)(1 * Hh + jb + l15) * K + l4 * 8;
  const size_t off2 = (size_t)(2 * Hh + jb + l15) * K + l4 * 8;

  const float* bb = layer ? b1 : b0;
  const f32x4 bi = *(const f32x4*)(bb + j0);
  const f32x4 bg = *(const f32x4*)(bb + Hh + j0);
  const f32x4 bo = *(const f32x4*)(bb + 2 * Hh + j0);

  float* cst = (layer ? c1 : c0) + (size_t)bact * Hh + j0;
  float* outb = out + (size_t)bact * Ss * Hh + j0;
  const float emag = __expf(mag[0]);

  // ---- prologue: W slice (48 rows x 1536 cols from KB) -> LDS ----
  {
    const u64* wsl = (const u64*)wf;
    const int K4 = K >> 2;
    const int cb4 = KB >> 2;
    for (int q = tid; q < 48 * 384; q += 512) {
      int R = q / 384;                   // 0..47 = g*16 + rr
      int o = q - R * 384;               // u64 col within LDS window
      int g = R >> 4, rr = R & 15;
      u64 v = wsl[(size_t)(g * Hh + jb + rr) * K4 + cb4 + o];
      *(u64*)(lds + (o >> 3) * CHUNKB + g * 1024 + ((o >> 1) & 3) * 256 +
              rr * 16 + (o & 1) * 8) = v;
    }
  }
  __syncthreads();

  f32x4 aI0, aG0, aO0, aI1, aG1, aO1;
  ZACC();
  f16x8 xp[8];
  if (layer == 0) { XPREF8(0); XCOMP8(); }   // prework for phase 0

  for (int p = 0; p < NPH; ++p) {
    const bool act = layer ? (p >= 1) : (p < Ss);
    const int t = layer ? (p - 1) : p;
    const int rslot = (p - 1) & (RING - 1);
    const int wslot = p & (RING - 1);

    if (act) {
      // ---- post-barrier tail: the only phase-serial GEMM work ----
      const unsigned short* hr =
          (layer ? h1f : h0f) + (size_t)rslot * BH + (size_t)bact * Hh + l4 * 8;
      if (kh == 0) {
        f16x8 hA[8], hB[8];
        HLOAD(hA, 8, hr, 0); HLOAD(hB, 8, hr, 256);
        HCOMP(hA, 8, 16); HCOMP(hB, 8, 24);
      } else {
        f16x8 hA[8], hB[8];
        HLOAD(hA, 8, hr, 512); HLOAD(hB, 8, hr, 768);
        HCOMP(hA, 8, 32); HCOMP(hB, 8, 40);
      }

      if (kh == 1) {
        red[((mt * 3 + 0) << 6) + lane] = aI0 + aI1;
        red[((mt * 3 + 1) << 6) + lane] = aG0 + aG1;
        red[((mt * 3 + 2) << 6) + lane] = aO0 + aO1;
      }
      __syncthreads();
      if (kh == 0) {
        f32x4 ai = aI0 + aI1 + red[((mt * 3 + 0) << 6) + lane] + bi;
        f32x4 ag = aG0 + aG1 + red[((mt * 3 + 1) << 6) + lane] + bg;
        f32x4 ao = aO0 + aO1 + red[((mt * 3 + 2) << 6) + lane] + bo;
        f32x4 cp = *(const f32x4*)cst;
        f32x4 cn, hn;
        u64 hpk = 0;
#pragma unroll
        for (int r = 0; r < 4; ++r) {
          float f = sig_(cp[r]);                   // forget gate from c_prev (quirk)
          float cc = f * cp[r] + sig_(ai[r]) * tanh_(ag[r]);
          float hh = sig_(ao[r]) * tanh_(cc) * f;  // extra *f (quirk)
          cn[r] = cc; hn[r] = hh;
          hpk |= (u64)f16b(hh) << (16 * r);
        }
        *(f32x4*)cst = cn;
        const size_t wbase = (size_t)wslot * BH + (size_t)bact * Hh + j0;
        __hip_atomic_store((u64*)((layer ? h1f : h0f) + wbase), hpk,
                           __ATOMIC_RELAXED, __HIP_MEMORY_SCOPE_AGENT);
        if (layer) {
          *(f32x4*)(outb + (size_t)t * Hh) = hn;
          if (t == Ss - 1) {
            *(f32x4*)(out + OF_H1 + (size_t)bact * Hh + j0) = hn;
            *(f32x4*)(out + OF_C1 + (size_t)bact * Hh + j0) = cn;
          }
        } else if (t == Ss - 1) {
          *(f32x4*)(out + OF_H0 + (size_t)bact * Hh + j0) = hn;
          *(f32x4*)(out + OF_C0 + (size_t)bact * Hh + j0) = cn;
        }
      }
    }

    // ---- barrier section with PREWORK (wave0-only polling) ----
    if (p < NPH - 1) {
      __syncthreads();   // main done; vmcnt drained -> h stores at LLC
      // ring-boundary inv BEFORE any new-window reads (prework included)
      if ((p & (RING - 1)) == (RING - 1)) {
        if (tid == 0) __builtin_amdgcn_fence(__ATOMIC_ACQUIRE, "agent");
        __syncthreads();
      }
      if (tid == 0)
        __hip_atomic_store(&slots[(dom * 64 + idx) * SSTR], p + 1,
                           __ATOMIC_RELAXED, __HIP_MEMORY_SCOPE_AGENT);

      if (layer == 1) {
        // partner gate: h0[t=p] ready (L0 epoch >= p+1) before prework reads
        if (wv == 0) poll1(slots, pdom * 64, p + 1, lane);
        __syncthreads();
        // prework(p+1): full h0-part (no h1 dependence)
        ZACC();
        const unsigned short* h0n =
            h0f + (size_t)(p & (RING - 1)) * BH + (size_t)bact * Hh + l4 * 8;
        if (kh == 0) {  // W K[0,512) streamed from global (L2-resident now)
          {
            f16x8 sh[8], sA[8], sB[8], sC[8];
            HLOAD(sh, 8, h0n, 0); WLOAD(sA, sB, sC, 8, 0);
            GCOMP(sh, sA, sB, sC, 8);
          }
          {
            f16x8 sh[8], sA[8], sB[8], sC[8];
            HLOAD(sh, 8, h0n, 256); WLOAD(sA, sB, sC, 8, 256);
            GCOMP(sh, sA, sB, sC, 8);
          }
        } else {        // W K[512,1024) = LDS chunks 0..15
          f16x8 hA[8], hB[8];
          HLOAD(hA, 8, h0n, 512); HLOAD(hB, 8, h0n, 768);
          HCOMP(hA, 8, 0); HCOMP(hB, 8, 8);
        }
        // own-domain barrier: h1[t=p] ready (hidden behind prework)
        if (wv == 0) poll1(slots, dom * 64, p + 1, lane);
        __syncthreads();
      } else {
        // L0 prework(p+1): x part (no dependence at all)
        if (p + 1 < Ss) { XPREF8(p + 1); ZACC(); XCOMP8(); }
        // own-domain barrier + ring-overwrite backpressure
        if (wv == 0) poll2(slots, dom * 64, p + 1, pdom * 64, p + 1 - LAG, lane);
        __syncthreads();
      }
    }
  }
}

// ---------------------------------------------------------------------------
extern "C" void kernel_launch(void* const* d_in, const int* in_sizes, int n_in,
                              void* d_out, int out_size, void* d_ws, size_t ws_size,
                              hipStream_t stream) {
  const float* x   = (const float*)d_in[0];
  const float* fw  = (const float*)d_in[1];
  const float* tw  = (const float*)d_in[2];
  const float* mag = (const float*)d_in[3];
  const float* W0  = (const float*)d_in[4];
  const float* b0  = (const float*)d_in[5];
  const float* W1  = (const float*)d_in[6];
  const float* b1  = (const float*)d_in[7];
  float* out = (float*)d_out;
  char* ws = (char*)d_ws;

  if (ws_size < WS_NEED) return;

  unsigned short* w0f = (unsigned short*)(ws + WS_W0F);
  unsigned short* w1f = (unsigned short*)(ws + WS_W1F);

  (void)hipFuncSetAttribute((const void*)lstm_persist,
                            hipFuncAttributeMaxDynamicSharedMemorySize, DYN_LDS);

  k_zero<<<768, 256, 0, stream>>>((uint4*)ws, (int)(WS_ZEND / 16));
  k_convert<<<1024, 256, 0, stream>>>(W0, W1, w0f, w1f);

  lstm_persist<<<NWG, 512, DYN_LDS, stream>>>(
      x, fw, tw, mag, w0f, b0, w1f, b1, out,
      (unsigned short*)(ws + WS_H0F), (unsigned short*)(ws + WS_H1F),
      (float*)(ws + WS_C0), (float*)(ws + WS_C1),
      (int*)(ws + WS_SLOTS));
}